// Round 9
// baseline (3281.985 us; speedup 1.0000x reference)
//
#include <hip/hip_runtime.h>
#include <math.h>

#define NROWS   65536
#define DIMS    64
#define KCODES  1024
#define RPB     128    // rows per main block

static constexpr size_t QST_OFF  = 0;         // quantized_st [65536*64]
static constexpr size_t LOSS_OFF = 4194304;   // loss scalar
static constexpr size_t PERP_OFF = 4194305;   // perplexity scalar
static constexpr size_t ENC_OFF  = 4194306;   // encodings [65536*1024]
static constexpr size_t IDX_OFF  = 71303170;  // encoding_indices [65536]
static constexpr size_t DIST_OFF = 71368706;  // distances [65536*1024]

// prep: blocks 0..255 -> xn per row (numpy pairwise, mul-then-add);
//       block 256 -> enorm (sequential d, mul-then-add) + embT transpose.
__global__ __launch_bounds__(256) void prep(
    const float* __restrict__ x, const float* __restrict__ emb,
    float* __restrict__ enorm, float* __restrict__ embT, float* __restrict__ xn)
{
    #pragma clang fp contract(off)
    const int tid = threadIdx.x;
    if (blockIdx.x < 256) {
        const int row = blockIdx.x * 256 + tid;
        const float* xr = x + (size_t)row * DIMS;
        float rr[8];
        #pragma unroll
        for (int j = 0; j < 8; ++j) { float v = xr[j]; rr[j] = v * v; }
        #pragma unroll
        for (int i = 8; i < 64; i += 8)
            #pragma unroll
            for (int j = 0; j < 8; ++j) { float v = xr[i + j]; float sq = v * v; rr[j] = rr[j] + sq; }
        xn[row] = ((rr[0] + rr[1]) + (rr[2] + rr[3])) + ((rr[4] + rr[5]) + (rr[6] + rr[7]));
    } else {
        #pragma unroll
        for (int c = 0; c < 4; ++c) {
            int k = c * 256 + tid;
            float s = 0.f;
            for (int d = 0; d < DIMS; ++d) {
                float e = emb[(size_t)d * KCODES + k];
                embT[(size_t)k * DIMS + d] = e;
                float sq = e * e;
                s = s + sq;
            }
            enorm[k] = s;
        }
    }
}

// Main: 512 blocks x 1024 thr. Thread = one k (e-column in 64 VGPRs).
// Block = 128 rows (x in LDS, staged once). The k-loop has NO global loads
// after the first store -> no vmcnt waits -> stores overlap compute fully.
__global__ __launch_bounds__(1024, 4) void vq_main(
    const float* __restrict__ x, const float* __restrict__ emb,
    const float* __restrict__ enorm, const float* __restrict__ embT,
    const float* __restrict__ xn, float* __restrict__ out,
    float* __restrict__ counts, float* __restrict__ sqsum)
{
    #pragma clang fp contract(off)
    __shared__ __align__(16) float xs[RPB * DIMS];        // 32 KB, row-major
    __shared__ float xnl[RPB];
    __shared__ unsigned long long wl[RPB][17];            // padded: no bank aliasing
    __shared__ int   wk[RPB];
    __shared__ float bsum[16];

    const int tid  = threadIdx.x;      // == this thread's k
    const int lane = tid & 63;
    const int wv   = tid >> 6;         // wave 0..15
    const size_t n0 = (size_t)blockIdx.x * RPB;

    // ---- prologue: ALL global loads happen here, before any store ----
    {   // x stage: linear copy, coalesced float4
        const float4* xg = (const float4*)(x + n0 * DIMS);
        float4 a = xg[tid], b = xg[tid + 1024];
        ((float4*)xs)[tid] = a; ((float4*)xs)[tid + 1024] = b;
    }
    if (tid < RPB) xnl[tid] = xn[n0 + tid];
    float ec[DIMS];                    // e column for k=tid -> 64 VGPRs
    #pragma unroll
    for (int d = 0; d < DIMS; ++d) ec[d] = emb[(size_t)d * KCODES + tid];
    const float en = enorm[tid];
    __syncthreads();

    // ---- main loop: 32 groups of 4 rows; LDS broadcasts + FMA + stores ----
    for (int g = 0; g < 32; ++g) {
        const int r0 = g * 4;
        float acc[4] = {0.f, 0.f, 0.f, 0.f};
        #pragma unroll
        for (int dq = 0; dq < 16; ++dq) {
            #pragma unroll
            for (int j = 0; j < 4; ++j) {   // sequential-d single-fma-chain per (row,k)
                float4 xv = *(const float4*)&xs[(r0 + j) * DIMS + dq * 4];
                acc[j] = fmaf(xv.x, ec[dq * 4 + 0], acc[j]);
                acc[j] = fmaf(xv.y, ec[dq * 4 + 1], acc[j]);
                acc[j] = fmaf(xv.z, ec[dq * 4 + 2], acc[j]);
                acc[j] = fmaf(xv.w, ec[dq * 4 + 3], acc[j]);
            }
        }
        #pragma unroll
        for (int j = 0; j < 4; ++j) {
            const int row = r0 + j;
            // np order: (xn - 2*M) + en, each op individually rounded
            float mm = 2.0f * acc[j];
            float tt = xnl[row] - mm;
            float dv = tt + en;
            const size_t rowg = n0 + row;
            out[DIST_OFF + rowg * (size_t)KCODES + tid] = dv;   // 1024 lanes contiguous
            out[ENC_OFF  + rowg * (size_t)KCODES + tid] = 0.f;

            // per-row argmin over all 1024 k: u64 key (exact float order, min-k tie)
            int ib = __float_as_int(dv);
            unsigned mk = (unsigned)ib ^ ((unsigned)(ib >> 31) | 0x80000000u);
            unsigned long long key = ((unsigned long long)mk << 32) | (unsigned)tid;
            #pragma unroll
            for (int m = 1; m < 64; m <<= 1) {
                unsigned long long ok = __shfl_xor(key, m);
                if (ok < key) key = ok;
            }
            if (lane == 0) wl[row][wv] = key;
        }
    }

    __syncthreads();   // single drain: all dist/enc zeros complete

    // ---- finals: winner per row, idx, counts, one-hot ----
    if (tid < RPB) {
        unsigned long long best = wl[tid][0];
        #pragma unroll
        for (int w = 1; w < 16; ++w) { unsigned long long o = wl[tid][w]; if (o < best) best = o; }
        int k = (int)(best & 1023u);
        wk[tid] = k;
        out[IDX_OFF + n0 + tid] = (float)k;
        atomicAdd(&counts[k], 1.0f);
        out[ENC_OFF + (n0 + tid) * (size_t)KCODES + k] = 1.0f;  // after drain: zeros are in L2
    }
    __syncthreads();

    // ---- qst gather (embT, L2-resident) + squared error ----
    {
        const int row = tid >> 3;
        const int q   = tid & 7;         // 8 floats per thread
        const int k   = wk[row];
        const float* et = embT + (size_t)k * DIMS + q * 8;
        float4 e0 = *(const float4*)(et);
        float4 e1 = *(const float4*)(et + 4);
        float* qo = out + QST_OFF + (n0 + row) * (size_t)DIMS + q * 8;
        *(float4*)qo = e0; *(float4*)(qo + 4) = e1;
        const float* xr = xs + row * DIMS + q * 8;
        float4 x0 = *(const float4*)(xr);
        float4 x1 = *(const float4*)(xr + 4);
        float f0 = e0.x - x0.x, f1 = e0.y - x0.y, f2 = e0.z - x0.z, f3 = e0.w - x0.w;
        float f4 = e1.x - x1.x, f5 = e1.y - x1.y, f6 = e1.z - x1.z, f7 = e1.w - x1.w;
        float ls = f0*f0 + f1*f1 + f2*f2 + f3*f3 + f4*f4 + f5*f5 + f6*f6 + f7*f7;
        #pragma unroll
        for (int m = 1; m < 64; m <<= 1) ls += __shfl_xor(ls, m);
        if (lane == 0) bsum[wv] = ls;
    }
    __syncthreads();
    if (tid == 0) {
        float s = 0.f;
        #pragma unroll
        for (int i = 0; i < 16; ++i) s += bsum[i];
        atomicAdd(sqsum, s);
    }
}

__global__ void vq_final(const float* __restrict__ counts, const float* __restrict__ sqsum,
                         float* __restrict__ out) {
    __shared__ double part[16];
    int tid = threadIdx.x;  // 1024 threads
    double p = (double)counts[tid] * (1.0 / 65536.0);
    double t = p * log(p + 1e-10);
    #pragma unroll
    for (int m = 1; m < 64; m <<= 1) t += __shfl_xor(t, m);
    if ((tid & 63) == 0) part[tid >> 6] = t;
    __syncthreads();
    if (tid == 0) {
        double s = 0.0;
        #pragma unroll
        for (int i = 0; i < 16; ++i) s += part[i];
        out[LOSS_OFF] = (float)(1.25 * (double)sqsum[0] * (1.0 / 4194304.0));
        out[PERP_OFF] = (float)exp(-s);
    }
}

extern "C" void kernel_launch(void* const* d_in, const int* in_sizes, int n_in,
                              void* d_out, int out_size, void* d_ws, size_t ws_size,
                              hipStream_t stream) {
    const float* x   = (const float*)d_in[0];   // (64,32,32,64) fp32
    const float* emb = (const float*)d_in[1];   // (64,1024) fp32
    float* out = (float*)d_out;
    // ws (floats): enorm[0,1024) | counts[1024,2048) | sqsum[2048] |
    // xn @4096 [65536] | embT @69632 [65536]   (~528 KB)
    float* enorm  = (float*)d_ws;
    float* counts = enorm + KCODES;
    float* sqsum  = counts + KCODES;
    float* xn     = (float*)d_ws + 4096;
    float* embT   = (float*)d_ws + 4096 + NROWS;

    hipMemsetAsync(counts, 0, (KCODES + 1) * sizeof(float), stream);
    prep<<<257, 256, 0, stream>>>(x, emb, enorm, embT, xn);
    vq_main<<<NROWS / RPB, 1024, 0, stream>>>(x, emb, enorm, embT, xn, out, counts, sqsum);
    vq_final<<<1, KCODES, 0, stream>>>(counts, sqsum, out);
}

// Round 10
// 460.377 us; speedup vs baseline: 7.1289x; 7.1289x over previous
//
#include <hip/hip_runtime.h>
#include <math.h>

#define NROWS   65536
#define DIMS    64
#define KCODES  1024

static constexpr size_t QST_OFF  = 0;         // quantized_st [65536*64]
static constexpr size_t LOSS_OFF = 4194304;   // loss scalar
static constexpr size_t PERP_OFF = 4194305;   // perplexity scalar
static constexpr size_t ENC_OFF  = 4194306;   // encodings [65536*1024]
static constexpr size_t IDX_OFF  = 71303170;  // encoding_indices [65536]
static constexpr size_t DIST_OFF = 71368706;  // distances [65536*1024]

// prep: blocks 0..255 -> xn per row (numpy pairwise, mul-then-add);
//       block 256 -> enorm (sequential d, mul-then-add).
__global__ __launch_bounds__(256) void prep(
    const float* __restrict__ x, const float* __restrict__ emb,
    float* __restrict__ enorm, float* __restrict__ xn)
{
    #pragma clang fp contract(off)
    const int tid = threadIdx.x;
    if (blockIdx.x < 256) {
        const int row = blockIdx.x * 256 + tid;
        const float* xr = x + (size_t)row * DIMS;
        float rr[8];
        #pragma unroll
        for (int j = 0; j < 8; ++j) { float v = xr[j]; rr[j] = v * v; }
        #pragma unroll
        for (int i = 8; i < 64; i += 8)
            #pragma unroll
            for (int j = 0; j < 8; ++j) { float v = xr[i + j]; float sq = v * v; rr[j] = rr[j] + sq; }
        xn[row] = ((rr[0] + rr[1]) + (rr[2] + rr[3])) + ((rr[4] + rr[5]) + (rr[6] + rr[7]));
    } else {
        #pragma unroll
        for (int c = 0; c < 4; ++c) {
            int k = c * 256 + tid;
            float s = 0.f;
            for (int d = 0; d < DIMS; ++d) {
                float e = emb[(size_t)d * KCODES + k];
                float sq = e * e;
                s = s + sq;
            }
            enorm[k] = s;
        }
    }
}

// Block = 64 rows x 512 k. 256 thr; thread owns k0+tid and k0+256+tid, with
// both e-columns resident in VGPRs (128 regs, statically indexed). x is read
// via wave-uniform addresses (no tid) -> scalar loads (lgkmcnt), so the main
// loop's global stores are never waited on (vmcnt holds only stores).
__global__ __launch_bounds__(256, 3) void vq_dist(
    const float* __restrict__ x, const float* __restrict__ emb,
    const float* __restrict__ enorm, const float* __restrict__ xn,
    float* __restrict__ out, unsigned long long* __restrict__ winners)
{
    #pragma clang fp contract(off)
    const int tid  = threadIdx.x;
    const int lane = tid & 63;
    const int k0   = (blockIdx.x & 1) * 512;
    const size_t r0 = (size_t)(blockIdx.x >> 1) * 64;

    // prologue: e-columns (coalesced: 256 lanes contiguous per d) + enorm
    float ec0[DIMS], ec1[DIMS];
    #pragma unroll
    for (int d = 0; d < DIMS; ++d) {
        ec0[d] = emb[(size_t)d * KCODES + (k0 + tid)];
        ec1[d] = emb[(size_t)d * KCODES + (k0 + 256 + tid)];
    }
    const float en0 = enorm[k0 + tid];
    const float en1 = enorm[k0 + 256 + tid];

    for (int rr = 0; rr < 64; ++rr) {
        const size_t row = r0 + rr;
        const float* __restrict__ xr = x + row * DIMS;   // uniform address -> s_load
        float a0 = 0.f, a1 = 0.f;
        #pragma unroll
        for (int d = 0; d < DIMS; ++d) {   // sequential-d single-fma-chain per (row,k)
            float xv = xr[d];
            a0 = fmaf(xv, ec0[d], a0);
            a1 = fmaf(xv, ec1[d], a1);
        }
        const float xnr = xn[row];          // uniform
        // np order: (xn - 2*M) + en, each op individually rounded
        float m0 = 2.0f * a0; float t0 = xnr - m0; float dv0 = t0 + en0;
        float m1 = 2.0f * a1; float t1 = xnr - m1; float dv1 = t1 + en1;

        float* dr = out + DIST_OFF + row * (size_t)KCODES + k0;
        dr[tid] = dv0; dr[tid + 256] = dv1;          // 256-lane contiguous dwords
        float* er = out + ENC_OFF + row * (size_t)KCODES + k0;
        er[tid] = 0.f; er[tid + 256] = 0.f;

        // wave-min (exact float copies -> exact equality test afterwards)
        float rm = fminf(dv0, dv1);
        #pragma unroll
        for (int m = 1; m < 64; m <<= 1) rm = fminf(rm, __shfl_xor(rm, m));
        unsigned long long b0 = __ballot(dv0 == rm);
        unsigned long long b1 = __ballot(dv1 == rm);
        // smallest k among matches: slot0 range (k0..k0+255) < slot1 range
        int winlane = b0 ? __builtin_ctzll(b0) : __builtin_ctzll(b1);
        if (lane == winlane) {
            int kw = b0 ? (k0 + tid) : (k0 + 256 + tid);
            int ib = __float_as_int(rm);
            unsigned mk = (unsigned)ib ^ ((unsigned)(ib >> 31) | 0x80000000u);
            unsigned long long key = ((unsigned long long)mk << 32) | (unsigned)kw;
            atomicMin(&winners[row], key);   // min value, then min k (tie)
        }
    }
}

// Pass 2: unpack winners -> qst gather, idx, enc one-hot, counts, sqsum
__global__ __launch_bounds__(256) void vq_finish(
    const float* __restrict__ x, const float* __restrict__ emb,
    const unsigned long long* __restrict__ winners, float* __restrict__ out,
    float* __restrict__ counts, float* __restrict__ sqsum)
{
    __shared__ float bsum[4];
    const int tid = threadIdx.x;
    const size_t row = (size_t)blockIdx.x * 16 + (tid >> 4);
    const int q = tid & 15;
    const int k = (int)(winners[row] & 1023u);

    float4 e4;
    e4.x = emb[(size_t)(q * 4 + 0) * KCODES + k];
    e4.y = emb[(size_t)(q * 4 + 1) * KCODES + k];
    e4.z = emb[(size_t)(q * 4 + 2) * KCODES + k];
    e4.w = emb[(size_t)(q * 4 + 3) * KCODES + k];
    float4 x4 = *(const float4*)(x + row * DIMS + q * 4);
    *(float4*)(out + QST_OFF + row * DIMS + q * 4) = e4;

    float f0 = e4.x - x4.x, f1 = e4.y - x4.y, f2 = e4.z - x4.z, f3 = e4.w - x4.w;
    float ls = f0 * f0 + f1 * f1 + f2 * f2 + f3 * f3;
    #pragma unroll
    for (int m = 1; m < 64; m <<= 1) ls += __shfl_xor(ls, m);
    if ((tid & 63) == 0) bsum[tid >> 6] = ls;

    if (q == 0) {
        out[IDX_OFF + row] = (float)k;
        atomicAdd(&counts[k], 1.0f);
        out[ENC_OFF + row * (size_t)KCODES + k] = 1.0f;   // zeros by vq_dist (prior kernel)
    }
    __syncthreads();
    if (tid == 0) atomicAdd(sqsum, (bsum[0] + bsum[1]) + (bsum[2] + bsum[3]));
}

__global__ void vq_final(const float* __restrict__ counts, const float* __restrict__ sqsum,
                         float* __restrict__ out) {
    __shared__ double part[16];
    int tid = threadIdx.x;  // 1024 threads
    double p = (double)counts[tid] * (1.0 / 65536.0);
    double t = p * log(p + 1e-10);
    #pragma unroll
    for (int m = 1; m < 64; m <<= 1) t += __shfl_xor(t, m);
    if ((tid & 63) == 0) part[tid >> 6] = t;
    __syncthreads();
    if (tid == 0) {
        double s = 0.0;
        #pragma unroll
        for (int i = 0; i < 16; ++i) s += part[i];
        out[LOSS_OFF] = (float)(1.25 * (double)sqsum[0] * (1.0 / 4194304.0));
        out[PERP_OFF] = (float)exp(-s);
    }
}

extern "C" void kernel_launch(void* const* d_in, const int* in_sizes, int n_in,
                              void* d_out, int out_size, void* d_ws, size_t ws_size,
                              hipStream_t stream) {
    const float* x   = (const float*)d_in[0];   // (64,32,32,64) fp32
    const float* emb = (const float*)d_in[1];   // (64,1024) fp32
    float* out = (float*)d_out;
    // ws (floats): enorm[0,1024) | counts[1024,2048) | sqsum[2048] |
    // xn @4096 [65536] | winners u64 @ float-offset 69632 (512 KB)
    float* enorm  = (float*)d_ws;
    float* counts = enorm + KCODES;
    float* sqsum  = counts + KCODES;
    float* xn     = (float*)d_ws + 4096;
    unsigned long long* winners = (unsigned long long*)((float*)d_ws + 69632);

    hipMemsetAsync(counts, 0, (KCODES + 1) * sizeof(float), stream);
    hipMemsetAsync(winners, 0xFF, NROWS * sizeof(unsigned long long), stream);
    prep<<<257, 256, 0, stream>>>(x, emb, enorm, xn);
    vq_dist<<<(NROWS / 64) * 2, 256, 0, stream>>>(x, emb, enorm, xn, out, winners);
    vq_finish<<<NROWS / 16, 256, 0, stream>>>(x, emb, winners, out, counts, sqsum);
    vq_final<<<1, KCODES, 0, stream>>>(counts, sqsum, out);
}